// Round 2
// baseline (357.863 us; speedup 1.0000x reference)
//
#include <hip/hip_runtime.h>

#define T_LEN 1024

typedef _Float16 f16x8 __attribute__((ext_vector_type(8)));
typedef float    f32x4 __attribute__((ext_vector_type(4)));

// tanh(v) = 1 - 2/(exp(2v)+1); exp(2v) = exp2(v * 2*log2(e))
__device__ __forceinline__ float tanh_fast(float v) {
    float e = exp2f(v * 2.88539008177792681472f);   // v_exp_f32
    return fmaf(-2.0f, __builtin_amdgcn_rcpf(e + 1.0f), 1.0f);
}

// One wave (64 threads) per block; block owns 16 batch rows for all T steps.
// Recurrence as C[m][n] = sum_k Whh[sigma(m)][k] * h[n][k] via mfma_f32_16x16x32_f16:
//   A-frag: A[m=lane&15][k=quad*8+j] = Whh[sigma(m)][k]   (static, f16)
//   B-frag: B[k=quad*8+j][n=lane&15] = h[row n][k]        (recirculated in-register)
//   C-frag: col n=lane&15 (batch row), row m=quad*4+reg (h index via sigma)
// sigma0(m)=8*(m>>2)+(m&3), sigma1=sigma0+4  ==> lane's C outputs are exactly
// h[n][8*quad + 0..7] == its own B-fragment slots for the next step. No LDS/shuffle.
__global__ __launch_bounds__(64) void rnn_fused(
    const float* __restrict__ x,      // [B, T]
    const float* __restrict__ W_ih,   // [32,1]
    const float* __restrict__ W_hh,   // [32,32]
    const float* __restrict__ b_ih,   // [32]
    const float* __restrict__ b_hh,   // [32]
    const float* __restrict__ fc_w,   // [1,32]
    const float* __restrict__ fc_b,   // [1]
    float* __restrict__ out)          // [B]
{
    const int lane = threadIdx.x;
    const int n = lane & 15;   // batch row within tile (B-frag col / C col)
    const int q = lane >> 4;   // quad index

    // A fragments (W_hh rows, permuted by sigma), converted to f16 once.
    const int m = n;
    const int c0row = 8 * (m >> 2) + (m & 3);
    const int c1row = c0row + 4;
    f16x8 a0, a1;
#pragma unroll
    for (int j = 0; j < 8; ++j) {
        a0[j] = (_Float16)W_hh[c0row * 32 + q * 8 + j];
        a1[j] = (_Float16)W_hh[c1row * 32 + q * 8 + j];
    }

    // This lane produces h-columns c = 8q + i (i = 0..7).
    float wih[8], bias[8], fcw[8];
#pragma unroll
    for (int i = 0; i < 8; ++i) {
        int c = 8 * q + i;
        wih[i]  = W_ih[c];
        bias[i] = b_ih[c] + b_hh[c];
        fcw[i]  = fc_w[c];
    }

    const float* xrow = x + (size_t)(blockIdx.x * 16 + n) * T_LEN;
    float4 xa = *(const float4*)xrow;   // t = 0..3 (4 lanes/row redundant -> broadcast)

    f16x8 hb = {};          // B fragment: h[n][8q+j], starts at 0
    float hlast[8];
#pragma unroll
    for (int i = 0; i < 8; ++i) hlast[i] = 0.0f;

    for (int t4 = 0; t4 < T_LEN / 4; ++t4) {
        const int nt4 = (t4 < T_LEN / 4 - 1) ? t4 + 1 : t4;   // prefetch next x chunk
        float4 xn = *(const float4*)(xrow + (size_t)nt4 * 4);
#pragma unroll
        for (int p = 0; p < 4; ++p) {
            const float xt = (p == 0) ? xa.x : (p == 1) ? xa.y : (p == 2) ? xa.z : xa.w;
            f32x4 acc0, acc1;
#pragma unroll
            for (int i = 0; i < 4; ++i) {
                acc0[i] = fmaf(xt, wih[i],     bias[i]);   // xi folded as C-init
                acc1[i] = fmaf(xt, wih[4 + i], bias[4 + i]);
            }
            acc0 = __builtin_amdgcn_mfma_f32_16x16x32_f16(a0, hb, acc0, 0, 0, 0);
            acc1 = __builtin_amdgcn_mfma_f32_16x16x32_f16(a1, hb, acc1, 0, 0, 0);

            f16x8 nb;
#pragma unroll
            for (int i = 0; i < 4; ++i) {
                const float h0 = tanh_fast(acc0[i]);
                const float h1 = tanh_fast(acc1[i]);
                hlast[i]     = h0;
                hlast[4 + i] = h1;
                nb[i]     = (_Float16)h0;   // v_cvt_f16_f32 (RNE)
                nb[4 + i] = (_Float16)h1;
            }
            hb = nb;
        }
        xa = xn;
    }

    // Head: out[r] = sum_c h[r][c] * fc_w[c] + fc_b  (use pre-f16 fp32 h values)
    float part = 0.0f;
#pragma unroll
    for (int i = 0; i < 8; ++i) part = fmaf(hlast[i], fcw[i], part);
    part += __shfl_xor(part, 16);
    part += __shfl_xor(part, 32);
    if (q == 0) out[blockIdx.x * 16 + n] = part + fc_b[0];
}

extern "C" void kernel_launch(void* const* d_in, const int* in_sizes, int n_in,
                              void* d_out, int out_size, void* d_ws, size_t ws_size,
                              hipStream_t stream) {
    const float* x    = (const float*)d_in[0];
    const float* W_ih = (const float*)d_in[1];
    const float* W_hh = (const float*)d_in[2];
    const float* b_ih = (const float*)d_in[3];
    const float* b_hh = (const float*)d_in[4];
    const float* fc_w = (const float*)d_in[5];
    const float* fc_b = (const float*)d_in[6];
    float* out = (float*)d_out;

    const int B = in_sizes[0] / T_LEN;   // 16384
    rnn_fused<<<B / 16, 64, 0, stream>>>(x, W_ih, W_hh, b_ih, b_hh, fc_w, fc_b, out);
}

// Round 3
// 275.876 us; speedup vs baseline: 1.2972x; 1.2972x over previous
//
#include <hip/hip_runtime.h>

#define T_LEN 1024

typedef _Float16 f16x8 __attribute__((ext_vector_type(8)));
typedef float    f32x4 __attribute__((ext_vector_type(4)));

// One wave (64 threads) per block; block owns 16 batch rows for all T steps.
// Recurrence as C[m][n] = sum_k Whh[sigma(m)][k] * h[n][k] via mfma_f32_16x16x32_f16:
//   A-frag: A[m=lane&15][k=quad*8+j] = Whh[sigma(m)][k]   (static, f16)
//   B-frag: B[k=quad*8+j][n=lane&15] = h[row n][k]        (recirculated in-register)
//   C-frag: col n=lane&15 (batch row), row m=quad*4+reg (h index via sigma)
// sigma0(m)=8*(m>>2)+(m&3), sigma1=sigma0+4  ==> lane's C outputs are exactly
// h[n][8*quad + 0..7] == its own B-fragment slots for the next step. No LDS/shuffle.
// All elementwise math on f32x4 vectors so LLVM emits v_pk_*_f32 (2 elems/instr).
__global__ __launch_bounds__(64) void rnn_fused(
    const float* __restrict__ x,      // [B, T]
    const float* __restrict__ W_ih,   // [32,1]
    const float* __restrict__ W_hh,   // [32,32]
    const float* __restrict__ b_ih,   // [32]
    const float* __restrict__ b_hh,   // [32]
    const float* __restrict__ fc_w,   // [1,32]
    const float* __restrict__ fc_b,   // [1]
    float* __restrict__ out)          // [B]
{
    const int lane = threadIdx.x;
    const int n = lane & 15;   // batch row within tile (B-frag col / C col)
    const int q = lane >> 4;   // quad index

    // A fragments (W_hh rows, permuted by sigma), converted to f16 once.
    const int c0row = 8 * (n >> 2) + (n & 3);
    const int c1row = c0row + 4;
    f16x8 a0, a1;
#pragma unroll
    for (int j = 0; j < 8; ++j) {
        a0[j] = (_Float16)W_hh[c0row * 32 + q * 8 + j];
        a1[j] = (_Float16)W_hh[c1row * 32 + q * 8 + j];
    }

    // This lane produces h-columns c = 8q + i (i = 0..7), as two f32x4 groups.
    f32x4 wih0, wih1, bias0, bias1, fcw0, fcw1;
#pragma unroll
    for (int i = 0; i < 4; ++i) {
        int c = 8 * q + i;
        wih0[i]  = W_ih[c];         wih1[i]  = W_ih[c + 4];
        bias0[i] = b_ih[c] + b_hh[c];
        bias1[i] = b_ih[c + 4] + b_hh[c + 4];
        fcw0[i]  = fc_w[c];         fcw1[i]  = fc_w[c + 4];
    }

    const float* xrow = x + (size_t)(blockIdx.x * 16 + n) * T_LEN;
    float4 xa = *(const float4*)xrow;   // t = 0..3 (4 lanes/row redundant -> broadcast)

    f16x8 hb = {};          // B fragment: h[n][8q+j], starts at 0
    f32x4 hl0 = {}, hl1 = {};           // last-step h in fp32 (for the head)

    const float K2LOG2E = 2.88539008177792681472f;   // 2*log2(e)

    for (int t4 = 0; t4 < T_LEN / 4; ++t4) {
        const int nt4 = (t4 < T_LEN / 4 - 1) ? t4 + 1 : t4;   // prefetch next x chunk
        float4 xn = *(const float4*)(xrow + (size_t)nt4 * 4);
#pragma unroll
        for (int p = 0; p < 4; ++p) {
            const float xt = (p == 0) ? xa.x : (p == 1) ? xa.y : (p == 2) ? xa.z : xa.w;
            const f32x4 xt4 = {xt, xt, xt, xt};
            // xi folded as C-init: v_pk_fma_f32 x2 per group
            f32x4 acc0 = __builtin_elementwise_fma(xt4, wih0, bias0);
            f32x4 acc1 = __builtin_elementwise_fma(xt4, wih1, bias1);
            acc0 = __builtin_amdgcn_mfma_f32_16x16x32_f16(a0, hb, acc0, 0, 0, 0);
            acc1 = __builtin_amdgcn_mfma_f32_16x16x32_f16(a1, hb, acc1, 0, 0, 0);

            // tanh(v) = 1 - 2/(exp2(v*2log2e)+1); pk mul/add/fma + scalar exp/rcp
            f32x4 t0 = acc0 * K2LOG2E;
            f32x4 t1 = acc1 * K2LOG2E;
            f32x4 e0, e1;
#pragma unroll
            for (int j = 0; j < 4; ++j) { e0[j] = __builtin_amdgcn_exp2f(t0[j]); }
#pragma unroll
            for (int j = 0; j < 4; ++j) { e1[j] = __builtin_amdgcn_exp2f(t1[j]); }
            f32x4 d0 = e0 + 1.0f;
            f32x4 d1 = e1 + 1.0f;
            f32x4 r0, r1;
#pragma unroll
            for (int j = 0; j < 4; ++j) { r0[j] = __builtin_amdgcn_rcpf(d0[j]); }
#pragma unroll
            for (int j = 0; j < 4; ++j) { r1[j] = __builtin_amdgcn_rcpf(d1[j]); }
            const f32x4 m2 = {-2.0f, -2.0f, -2.0f, -2.0f};
            const f32x4 one = {1.0f, 1.0f, 1.0f, 1.0f};
            hl0 = __builtin_elementwise_fma(r0, m2, one);
            hl1 = __builtin_elementwise_fma(r1, m2, one);

            f16x8 nb;
#pragma unroll
            for (int i = 0; i < 4; ++i) {
                nb[i]     = (_Float16)hl0[i];   // v_cvt_f16_f32 (RNE)
                nb[4 + i] = (_Float16)hl1[i];
            }
            hb = nb;
        }
        xa = xn;
    }

    // Head: out[r] = sum_c h[r][c] * fc_w[c] + fc_b  (use fp32 h values)
    float part = 0.0f;
#pragma unroll
    for (int i = 0; i < 4; ++i) {
        part = fmaf(hl0[i], fcw0[i], part);
        part = fmaf(hl1[i], fcw1[i], part);
    }
    part += __shfl_xor(part, 16);
    part += __shfl_xor(part, 32);
    if (q == 0) out[blockIdx.x * 16 + n] = part + fc_b[0];
}

extern "C" void kernel_launch(void* const* d_in, const int* in_sizes, int n_in,
                              void* d_out, int out_size, void* d_ws, size_t ws_size,
                              hipStream_t stream) {
    const float* x    = (const float*)d_in[0];
    const float* W_ih = (const float*)d_in[1];
    const float* W_hh = (const float*)d_in[2];
    const float* b_ih = (const float*)d_in[3];
    const float* b_hh = (const float*)d_in[4];
    const float* fc_w = (const float*)d_in[5];
    const float* fc_b = (const float*)d_in[6];
    float* out = (float*)d_out;

    const int B = in_sizes[0] / T_LEN;   // 16384
    rnn_fused<<<B / 16, 64, 0, stream>>>(x, W_ih, W_hh, b_ih, b_hh, fc_w, fc_b, out);
}